// Round 12
// baseline (122.854 us; speedup 1.0000x reference)
//
#include <hip/hip_runtime.h>
#include <hip/hip_bf16.h>
#include <cstdint>

#define IN_F 256
#define OUT_F 64
#define NB 4
#define NN 4096
#define ALPHA 0.2f
#define LOG2E 1.4426950408889634f

typedef __attribute__((ext_vector_type(4))) float f32x4;
typedef __attribute__((ext_vector_type(4))) int i32x4;
typedef __attribute__((ext_vector_type(8))) short bf16x8;

static __device__ __forceinline__ ushort f2bf(float x) {
  uint32_t u = __float_as_uint(x);
  uint32_t r = (u + 0x7fffu + ((u >> 16) & 1u)) >> 16;
  return (ushort)r;
}

// async global -> LDS, 16B per lane
static __device__ __forceinline__ void gl16(const void* g, void* l) {
  __builtin_amdgcn_global_load_lds(
      (const __attribute__((address_space(1))) void*)g,
      (__attribute__((address_space(3))) void*)l, 16, 0, 0);
}
#define FENCE() asm volatile("" ::: "memory")

// ---------------- Kernel 01 (merged): blocks 0..1023 = DMA-staged adj bit-pack,
// blocks 1024..1535 = gemm.
// pack: adj rows staged via 4-deep global_load_lds ring (counted vmcnt + raw
//       s_barrier — the path that measured 5.6 TB/s in round 6). Ballot from
//       LDS (ds_read_b32 x4 at col offsets {l,64+l,128+l,192+l}, 2-way banks)
//       -> natural bit layout: mask[b][cb][n], bit l = col cb*64+l.
//       8KB LDS mask panel, coalesced 128B-run flush.
// gemm: Wh = h@W + bias; Wh1/Wh2 = (Wh.a1/a2)*LOG2E; WhT bf16 [B][64][N].
#define PK_LDS 73984   /* 4*16384 ring + 16*66*8 mask panel */
__global__ __launch_bounds__(256) void k01_pack_gemm(
    const float* __restrict__ h, const float* __restrict__ W,
    const float* __restrict__ a, const float* __restrict__ bias,
    const int* __restrict__ adj,
    ushort* __restrict__ WhT, float* __restrict__ Wh1, float* __restrict__ Wh2,
    unsigned long long* __restrict__ maskp)
{
  extern __shared__ char smem[];
  const int t = threadIdx.x;

  if (blockIdx.x < 1024) {
    // ---------------- pack part ----------------
    const int pbid = blockIdx.x;           // 0..1023
    const int b    = pbid >> 8;
    const int n0   = (pbid & 255) << 4;    // 16-row band
    const int l    = t & 63;
    const int w    = t >> 6;               // wave -> rows w*4..w*4+3
    unsigned long long* mlds = (unsigned long long*)(smem + 65536);  // [16][66]

    const int* adjb = adj + ((size_t)b << 24) + ((size_t)n0 << 12);
    const int* src_[4]; int ldsd[4];
    #pragma unroll
    for (int i = 0; i < 4; ++i) {
      int e = (i << 8) + t;                // 0..1023: row = e>>6, chunk = e&63
      src_[i] = adjb + ((size_t)(e >> 6) << 12) + ((e & 63) << 2);
      ldsd[i] = e << 4;
    }
    auto STAGE = [&](int s) {              // step s: 16 rows x 256 cols = 16KB
      char* base = smem + ((s & 3) << 14);
      #pragma unroll
      for (int i = 0; i < 4; ++i) gl16(src_[i] + (s << 8), base + ldsd[i]);
    };
    auto PCOMP = [&](int s) {
      const char* base = smem + ((s & 3) << 14);
      #pragma unroll
      for (int rr = 0; rr < 4; ++rr) {
        int row = (w << 2) + rr;
        const int* rp = (const int*)(base + (row << 10));
        int v0 = rp[l], v1 = rp[64 + l], v2 = rp[128 + l], v3 = rp[192 + l];
        unsigned long long m0 = __ballot(v0 != 0);
        unsigned long long m1 = __ballot(v1 != 0);
        unsigned long long m2 = __ballot(v2 != 0);
        unsigned long long m3 = __ballot(v3 != 0);
        if (l == 0) {
          unsigned long long* mp = mlds + row * 66 + (s << 2);
          mp[0] = m0; mp[1] = m1; mp[2] = m2; mp[3] = m3;
        }
      }
    };

    STAGE(0); STAGE(1); STAGE(2);
    FENCE();
    for (int s = 0; s < 16; ++s) {
      if (s < 14)      asm volatile("s_waitcnt vmcnt(8)" ::: "memory");
      else if (s == 14) asm volatile("s_waitcnt vmcnt(4)" ::: "memory");
      else              asm volatile("s_waitcnt vmcnt(0)" ::: "memory");
      __builtin_amdgcn_s_barrier();
      PCOMP(s);
      FENCE();
      if (s < 13) STAGE(s + 3);
      FENCE();
    }
    __syncthreads();
    // coalesced flush: [b][cb][n], per cb a 128B run of 16 rows
    #pragma unroll
    for (int i = 0; i < 4; ++i) {
      int u = (i << 8) + t;                // 0..1023
      int word = u >> 4, row = u & 15;
      maskp[(((size_t)(b * 64 + word)) << 12) + n0 + row] = mlds[row * 66 + word];
    }
  } else {
    // ---------------- gemm part ----------------
    float (*hs)[33] = (float(*)[33])smem;             // 32x33 f32
    float (*Ws)[64] = (float(*)[64])(smem + 4224);    // 32x64 f32
    const int tx = t & 15;
    const int ty = t >> 4;
    const int row0 = (blockIdx.x - 1024) * 32;

    float acc[2][4] = {};

    for (int k0 = 0; k0 < IN_F; k0 += 32) {
      {
        int r = t >> 3, c4 = t & 7;
        *(f32x4*)&hs[r][c4 * 4] =
            *(const f32x4*)(h + (size_t)(row0 + r) * IN_F + k0 + c4 * 4);
      }
      #pragma unroll
      for (int s = 0; s < 2; ++s) {
        int f4 = t + 256 * s;
        int kk = f4 >> 4, c4 = f4 & 15;
        *(f32x4*)&Ws[kk][c4 * 4] = *(const f32x4*)(W + (size_t)(k0 + kk) * OUT_F + c4 * 4);
      }
      __syncthreads();
      #pragma unroll 8
      for (int kk = 0; kk < 32; ++kk) {
        f32x4 bv = *(const f32x4*)&Ws[kk][tx * 4];
        float av0 = hs[ty * 2 + 0][kk];
        float av1 = hs[ty * 2 + 1][kk];
        #pragma unroll
        for (int j = 0; j < 4; ++j) {
          acc[0][j] += av0 * bv[j];
          acc[1][j] += av1 * bv[j];
        }
      }
      __syncthreads();
    }

    #pragma unroll
    for (int i = 0; i < 2; ++i) {
      int row = row0 + ty * 2 + i;
      float s1 = 0.f, s2 = 0.f;
      #pragma unroll
      for (int j = 0; j < 4; ++j) {
        float v = acc[i][j] + bias[tx * 4 + j];
        acc[i][j] = v;
        s1 += v * a[tx * 4 + j];
        s2 += v * a[64 + tx * 4 + j];
      }
      #pragma unroll
      for (int off = 1; off < 16; off <<= 1) {
        s1 += __shfl_xor(s1, off);
        s2 += __shfl_xor(s2, off);
      }
      if (tx == 0) { Wh1[row] = s1 * LOG2E; Wh2[row] = s2 * LOG2E; }
      int bb = row >> 12;
      int n  = row & 4095;
      #pragma unroll
      for (int j = 0; j < 4; ++j) {
        WhT[(((size_t)(bb * OUT_F + tx * 4 + j)) << 12) + n] = f2bf(acc[i][j]);
      }
    }
  }
}

// ---------------- Kernel 2: fused masked softmax + PV, bitmask-fed (= round 10)
// grid (64, 4), 512 threads = 8 waves = (4 row-quarters) x (2 K-halves).
// Block: 64 rows x 64 out cols, K-step 64 cols, 64 steps.
// 32KB mask panel + 16KB Wh2 staged once in prologue; WhT tile ring
// (8KB/step, depth 4, L2-resident) with counted vmcnt + raw s_barrier.
// Mask read = 1 broadcast ds_read_u32/lane/step.
#define NDEPTH 4
#define WHT_BUF 8192
#define MASK_OFF 32768    /* 4*8192 */
#define WH2_OFF  65536    /* 32768 + 32768 */
#define LDS_TOTAL 81920   /* + 16384 */
__global__ __launch_bounds__(512, 1) void k2_attn(
    const unsigned long long* __restrict__ maskp, const ushort* __restrict__ WhT,
    const float* __restrict__ Wh1, const float* __restrict__ Wh2,
    float* __restrict__ out)
{
  extern __shared__ char smem[];
  const int t  = threadIdx.x;        // 0..511
  const int l  = t & 63;
  const int w  = t >> 6;             // 0..7
  const int rq = w >> 1;             // row quarter 0..3
  const int kq = w & 1;              // K half of the 64-col step
  const int g  = l >> 4;             // k-subgroup 0..3
  const int lr = l & 15;
  const int b  = blockIdx.y;
  const int r0 = blockIdx.x << 6;

  const int   rowl = rq * 16 + lr;
  const float wh1  = Wh1[(b << 12) + r0 + rowl];   // already * LOG2E
  asm volatile("" :: "v"(wh1));

  // ---- WhT staging: 1 gl16/thread/step (pre-inverse-swizzled source, rule 21)
  const ushort* whb = WhT + ((size_t)(b * OUT_F) << 12);
  const int fW = t >> 3, chW = (t & 7) ^ (fW & 7);
  const ushort* srcW = whb + ((size_t)fW << 12) + chW * 8;
  const int ldsW = t << 4;
  auto STAGE_W = [&](int s) {
    gl16(srcW + (s << 6), smem + (s & 3) * WHT_BUF + ldsW);
  };

  // ---- accumulators
  f32x4 a0 = {0.f,0.f,0.f,0.f}, a1 = {0.f,0.f,0.f,0.f};
  f32x4 a2 = {0.f,0.f,0.f,0.f}, a3 = {0.f,0.f,0.f,0.f};
  f32x4 as = {0.f,0.f,0.f,0.f};
  bf16x8 ones;
  #pragma unroll
  for (int i = 0; i < 8; ++i) ones[i] = (short)0x3F80;

  const int offW = (kq * 64 + g * 16) ^ ((lr & 7) << 4);
  const int moff = MASK_OFF + rowl * 8 + kq * 4;
  const int gsh  = g * 8;

  auto COMPUTE = [&](int s) {
    const char* baseW = smem + (s & 3) * WHT_BUF;
    bf16x8 b0 = *(const bf16x8*)(baseW + (lr     ) * 128 + offW);
    bf16x8 b1 = *(const bf16x8*)(baseW + (lr + 16) * 128 + offW);
    bf16x8 b2 = *(const bf16x8*)(baseW + (lr + 32) * 128 + offW);
    bf16x8 b3 = *(const bf16x8*)(baseW + (lr + 48) * 128 + offW);
    uint32_t mu  = *(const uint32_t*)(smem + moff + (s << 9));
    uint32_t mby = (mu >> gsh) & 0xffu;
    const char* w2b = smem + WH2_OFF + (s << 8) + kq * 128 + g * 32;
    f32x4 w20 = *(const f32x4*)(w2b);
    f32x4 w21 = *(const f32x4*)(w2b + 16);

    float p[8];
    #pragma unroll
    for (int i = 0; i < 8; ++i) {
      float w2 = (i < 4) ? w20[i] : w21[i - 4];
      float s_ = wh1 + w2;                                      // LOG2E-scaled
      float lk = fmaf(ALPHA, fminf(s_, 0.f), fmaxf(s_, 0.f));   // LeakyReLU
      float pe = exp2f(lk);
      p[i] = (mby & (1u << i)) ? pe : 0.0f;
    }
    union { bf16x8 v; uint32_t u[4]; } af;
    #pragma unroll
    for (int i = 0; i < 4; ++i)
      asm("v_cvt_pk_bf16_f32 %0, %1, %2" : "=v"(af.u[i]) : "v"(p[2*i]), "v"(p[2*i+1]));

    as = __builtin_amdgcn_mfma_f32_16x16x32_bf16(af.v, ones, as, 0, 0, 0);
    a0 = __builtin_amdgcn_mfma_f32_16x16x32_bf16(af.v, b0,   a0, 0, 0, 0);
    a1 = __builtin_amdgcn_mfma_f32_16x16x32_bf16(af.v, b1,   a1, 0, 0, 0);
    a2 = __builtin_amdgcn_mfma_f32_16x16x32_bf16(af.v, b2,   a2, 0, 0, 0);
    a3 = __builtin_amdgcn_mfma_f32_16x16x32_bf16(af.v, b3,   a3, 0, 0, 0);
  };

  // ---- prologue: mask panel (4), wh2 (2), WhT stages 0..2 (3) -> 9 in queue
  #pragma unroll
  for (int i = 0; i < 4; ++i) {
    int e  = (i << 9) + t;
    int cb = e >> 5, u = e & 31;
    const char* src = (const char*)maskp +
        ((((size_t)(b * 64 + cb)) << 12) + r0) * 8 + u * 16;
    gl16(src, smem + MASK_OFF + (e << 4));
  }
  {
    const float* w2src = Wh2 + (b << 12);
    gl16(w2src + (t << 2),         smem + WH2_OFF + (t << 4));
    gl16(w2src + ((t + 512) << 2), smem + WH2_OFF + 8192 + (t << 4));
  }
  FENCE();
  STAGE_W(0); STAGE_W(1); STAGE_W(2);
  FENCE();

  // ---- main loop: 64 steps, ring of 4, stage s+3 after compute, 1 barrier/step
  for (int s = 0; s < 64; ++s) {
    if (s < 62)      asm volatile("s_waitcnt vmcnt(2)" ::: "memory");
    else if (s == 62) asm volatile("s_waitcnt vmcnt(1)" ::: "memory");
    else              asm volatile("s_waitcnt vmcnt(0)" ::: "memory");
    __builtin_amdgcn_s_barrier();
    COMPUTE(s);
    FENCE();
    if (s < 61) STAGE_W(s + 3);
    FENCE();
  }

  // ---- epilogue: cross-kq combine via LDS overlay
  __syncthreads();
  float* sacc = (float*)smem;                  // [2][64][68]
  float* ssum = (float*)(smem + 34816);        // [2][64]
  #pragma unroll
  for (int r = 0; r < 4; ++r) {
    int rr = rq * 16 + g * 4 + r;              // C/D: row = 4*(l>>4)+r, col = l&15
    float* dst = sacc + (kq * 64 + rr) * 68;
    dst[ 0 + lr] = a0[r];
    dst[16 + lr] = a1[r];
    dst[32 + lr] = a2[r];
    dst[48 + lr] = a3[r];
    if (lr == 0) ssum[kq * 64 + rr] = as[r];
  }
  __syncthreads();

  const int row = t >> 3;               // 0..63
  const int c0  = (t & 7) << 3;         // 0..56
  const float* p0 = sacc + row * 68;
  const float* p1 = sacc + (64 + row) * 68;
  float d = ssum[row] + ssum[64 + row];
  float inv = 1.0f / d;
  f32x4 o0, o1;
  #pragma unroll
  for (int j = 0; j < 4; ++j) {
    float x = (p0[c0 + j] + p1[c0 + j]) * inv;
    o0[j] = x > 0.f ? x : expm1f(x);
    float y = (p0[c0 + 4 + j] + p1[c0 + 4 + j]) * inv;
    o1[j] = y > 0.f ? y : expm1f(y);
  }
  size_t ob = ((size_t)((b << 12) + r0 + row) << 6) + c0;
  *(f32x4*)(out + ob)     = o0;
  *(f32x4*)(out + ob + 4) = o1;
}

extern "C" void kernel_launch(void* const* d_in, const int* in_sizes, int n_in,
                              void* d_out, int out_size, void* d_ws, size_t ws_size,
                              hipStream_t stream) {
  const float* h    = (const float*)d_in[0];
  const int*   adj  = (const int*)d_in[1];
  const float* W    = (const float*)d_in[2];
  const float* a    = (const float*)d_in[3];
  const float* bias = (const float*)d_in[4];
  float* out = (float*)d_out;

  char* ws = (char*)d_ws;
  ushort* WhT = (ushort*)ws;                                   // 2 MB
  float*  Wh1 = (float*)(ws + (size_t)NB * OUT_F * NN * 2);    // 64 KB
  float*  Wh2 = Wh1 + NB * NN;                                 // 64 KB
  unsigned long long* maskp =
      (unsigned long long*)(ws + (size_t)NB * OUT_F * NN * 2 + 2 * NB * NN * 4);  // 8 MB

  (void)hipFuncSetAttribute((const void*)k01_pack_gemm,
                            hipFuncAttributeMaxDynamicSharedMemorySize, PK_LDS);
  (void)hipFuncSetAttribute((const void*)k2_attn,
                            hipFuncAttributeMaxDynamicSharedMemorySize, LDS_TOTAL);

  k01_pack_gemm<<<dim3(1024 + 512), 256, PK_LDS, stream>>>(h, W, a, bias, adj,
                                                           WhT, Wh1, Wh2, maskp);
  k2_attn<<<dim3(NN / 64, NB), 512, LDS_TOTAL, stream>>>(maskp, WhT, Wh1, Wh2, out);
}

// Round 13
// 74.439 us; speedup vs baseline: 1.6504x; 1.6504x over previous
//
#include <hip/hip_runtime.h>
#include <hip/hip_bf16.h>
#include <cstdint>

#define IN_F 256
#define OUT_F 64
#define NB 4
#define NN 4096
#define ALPHA 0.2f
#define LOG2E 1.4426950408889634f

typedef __attribute__((ext_vector_type(4))) float f32x4;
typedef __attribute__((ext_vector_type(4))) int i32x4;
typedef __attribute__((ext_vector_type(8))) short bf16x8;

static __device__ __forceinline__ ushort f2bf(float x) {
  uint32_t u = __float_as_uint(x);
  uint32_t r = (u + 0x7fffu + ((u >> 16) & 1u)) >> 16;
  return (ushort)r;
}

// async global -> LDS, 16B per lane
static __device__ __forceinline__ void gl16(const void* g, void* l) {
  __builtin_amdgcn_global_load_lds(
      (const __attribute__((address_space(1))) void*)g,
      (__attribute__((address_space(3))) void*)l, 16, 0, 0);
}

// ---------------- Kernel 1: Wh = h@W + bias; Wh1/Wh2 = (Wh.a1/a2)*LOG2E; WhT bf16 [B][64][N]
// 32 rows/block, 512 blocks -> 2 blocks/CU.
__global__ __launch_bounds__(256) void k1_gemm(
    const float* __restrict__ h, const float* __restrict__ W,
    const float* __restrict__ a, const float* __restrict__ bias,
    ushort* __restrict__ WhT, float* __restrict__ Wh1, float* __restrict__ Wh2)
{
  __shared__ float hs[32][33];
  __shared__ float Ws[32][64];
  const int t  = threadIdx.x;
  const int tx = t & 15;        // col group: cols tx*4..tx*4+3
  const int ty = t >> 4;        // row group: rows ty*2..ty*2+1
  const int row0 = blockIdx.x * 32;

  float acc[2][4] = {};

  for (int k0 = 0; k0 < IN_F; k0 += 32) {
    {                                             // h tile: 32x32 (one f32x4/thread)
      int r = t >> 3, c4 = t & 7;
      *(f32x4*)&hs[r][c4 * 4] =
          *(const f32x4*)(h + (size_t)(row0 + r) * IN_F + k0 + c4 * 4);
    }
    #pragma unroll
    for (int s = 0; s < 2; ++s) {                 // W tile: 32x64
      int f4 = t + 256 * s;
      int kk = f4 >> 4, c4 = f4 & 15;
      *(f32x4*)&Ws[kk][c4 * 4] = *(const f32x4*)(W + (size_t)(k0 + kk) * OUT_F + c4 * 4);
    }
    __syncthreads();
    #pragma unroll 8
    for (int kk = 0; kk < 32; ++kk) {
      f32x4 bv = *(const f32x4*)&Ws[kk][tx * 4];
      float av0 = hs[ty * 2 + 0][kk];
      float av1 = hs[ty * 2 + 1][kk];
      #pragma unroll
      for (int j = 0; j < 4; ++j) {
        acc[0][j] += av0 * bv[j];
        acc[1][j] += av1 * bv[j];
      }
    }
    __syncthreads();
  }

  #pragma unroll
  for (int i = 0; i < 2; ++i) {
    int row = row0 + ty * 2 + i;
    float s1 = 0.f, s2 = 0.f;
    #pragma unroll
    for (int j = 0; j < 4; ++j) {
      float v = acc[i][j] + bias[tx * 4 + j];
      acc[i][j] = v;
      s1 += v * a[tx * 4 + j];
      s2 += v * a[64 + tx * 4 + j];
    }
    #pragma unroll
    for (int off = 1; off < 16; off <<= 1) {
      s1 += __shfl_xor(s1, off);
      s2 += __shfl_xor(s2, off);
    }
    if (tx == 0) { Wh1[row] = s1 * LOG2E; Wh2[row] = s2 * LOG2E; }  // pre-scaled for exp2
    int bb = row >> 12;
    int n  = row & 4095;
    #pragma unroll
    for (int j = 0; j < 4; ++j) {
      WhT[(((size_t)(bb * OUT_F + tx * 4 + j)) << 12) + n] = f2bf(acc[i][j]);
    }
  }
}

// ---------------- Kernel 2: fused masked softmax + PV (round-6 champion structure)
// grid (64, 4), 512 threads = 8 waves = (4 row-quarters) x (2 K-halves).
// Block: 64 rows x 64 out cols, K-step 64 cols, 64 steps.
// 5-deep 24KB LDS ring (adj 16KB + wht 8KB per step), counted vmcnt(9) +
// raw s_barrier; Wh2 staged to LDS once; zero global loads in main loop.
// No softmax shift (cancels exactly in P/sum(P); |e| small in this regime).
// LOG2E prescaled in k1 -> exp2f(lk) directly. XOR swizzle both-sides.
#define BUFSZ 24576
#define NDEPTH 5
#define WH2_OFF 122880   /* 5*24576 */
#define LDS_TOTAL 139264 /* 5*24576 + 16384 */
__global__ __launch_bounds__(512) void k2_attn(
    const int* __restrict__ adj, const ushort* __restrict__ WhT,
    const float* __restrict__ Wh1, const float* __restrict__ Wh2,
    float* __restrict__ out)
{
  extern __shared__ char smem[];
  const int t  = threadIdx.x;        // 0..511
  const int l  = t & 63;
  const int w  = t >> 6;             // 0..7
  const int rq = w >> 1;             // row quarter 0..3
  const int kq = w & 1;              // K half of the 64-col step
  const int g  = l >> 4;             // k-subgroup 0..3
  const int lr = l & 15;
  const int b  = blockIdx.y;
  const int r0 = blockIdx.x << 6;

  const int   rowl  = rq * 16 + lr;                  // block-local A row
  const float wh1 = Wh1[(b << 12) + r0 + rowl];      // already * LOG2E
  asm volatile("" :: "v"(wh1));      // force load+wait before DMA pipeline starts

  // ---- staging source pointers (pre-inverse-swizzled, rule 21)
  const int*    adjb = adj + ((size_t)b << 24) + ((size_t)r0 << 12);
  const ushort* whb  = WhT + ((size_t)(b * OUT_F) << 12);
  const int rowA = t >> 4,           mlA = (t & 15) ^ (rowA & 7);
  const int rowB = (t + 512) >> 4,   mlB = (t & 15) ^ (rowB & 7);
  const int fW   = t >> 3,           mlW = (t & 7) ^ (fW & 7);
  const int*    srcA = adjb + (size_t)rowA * 4096 + mlA * 4;
  const int*    srcB = adjb + (size_t)rowB * 4096 + mlB * 4;
  const ushort* srcW = whb + ((size_t)fW << 12) + mlW * 8;
  const int ldsA = t << 4, ldsB = (t + 512) << 4, ldsW = 16384 + (t << 4);

  auto STAGE = [&](int s) {
    char* base = smem + (s % NDEPTH) * BUFSZ;
    gl16(srcA + s * 64, base + ldsA);
    gl16(srcB + s * 64, base + ldsB);
    gl16(srcW + s * 64, base + ldsW);
  };

  // ---- accumulators
  f32x4 a0 = {0.f,0.f,0.f,0.f}, a1 = {0.f,0.f,0.f,0.f};
  f32x4 a2 = {0.f,0.f,0.f,0.f}, a3 = {0.f,0.f,0.f,0.f};
  f32x4 as = {0.f,0.f,0.f,0.f};
  bf16x8 ones;
  #pragma unroll
  for (int i = 0; i < 8; ++i) ones[i] = (short)0x3F80;

  const int swzA = (rowl & 7) << 4;
  const int swzW = (lr & 7) << 4;
  const int offA0 = (kq * 128 + g * 32) ^ swzA;
  const int offA1 = (kq * 128 + g * 32 + 16) ^ swzA;
  const int offW  = (kq * 64 + g * 16) ^ swzW;

  auto COMPUTE = [&](int s) {
    const char* base = smem + (s % NDEPTH) * BUFSZ;
    i32x4 ad0 = *(const i32x4*)(base + rowl * 256 + offA0);
    i32x4 ad1 = *(const i32x4*)(base + rowl * 256 + offA1);
    const char* wb = base + 16384;
    bf16x8 b0 = *(const bf16x8*)(wb + (lr     ) * 128 + offW);
    bf16x8 b1 = *(const bf16x8*)(wb + (lr + 16) * 128 + offW);
    bf16x8 b2 = *(const bf16x8*)(wb + (lr + 32) * 128 + offW);
    bf16x8 b3 = *(const bf16x8*)(wb + (lr + 48) * 128 + offW);
    const char* w2b = smem + WH2_OFF + (s << 8) + kq * 128 + g * 32;
    f32x4 w20 = *(const f32x4*)(w2b);
    f32x4 w21 = *(const f32x4*)(w2b + 16);

    float p[8];
    #pragma unroll
    for (int i = 0; i < 8; ++i) {
      float w2 = (i < 4) ? w20[i] : w21[i - 4];
      int   am = (i < 4) ? ad0[i] : ad1[i - 4];
      float s_ = wh1 + w2;                                      // LOG2E-scaled
      float lk = fmaf(ALPHA, fminf(s_, 0.f), fmaxf(s_, 0.f));   // LeakyReLU
      float pe = exp2f(lk);                                     // unshifted, safe
      p[i] = (am > 0) ? pe : 0.0f;
    }
    union { bf16x8 v; uint32_t u[4]; } af;
    #pragma unroll
    for (int i = 0; i < 4; ++i)
      asm("v_cvt_pk_bf16_f32 %0, %1, %2" : "=v"(af.u[i]) : "v"(p[2*i]), "v"(p[2*i+1]));

    as = __builtin_amdgcn_mfma_f32_16x16x32_bf16(af.v, ones, as, 0, 0, 0);
    a0 = __builtin_amdgcn_mfma_f32_16x16x32_bf16(af.v, b0,   a0, 0, 0, 0);
    a1 = __builtin_amdgcn_mfma_f32_16x16x32_bf16(af.v, b1,   a1, 0, 0, 0);
    a2 = __builtin_amdgcn_mfma_f32_16x16x32_bf16(af.v, b2,   a2, 0, 0, 0);
    a3 = __builtin_amdgcn_mfma_f32_16x16x32_bf16(af.v, b3,   a3, 0, 0, 0);
  };

  // ---- prologue: stage wh2 (once, 2 loads) + steps 0..3 (12 loads)
  {
    const float* w2src = Wh2 + (b << 12);
    gl16(w2src + (t << 2),         smem + WH2_OFF + (t << 4));
    gl16(w2src + ((t + 512) << 2), smem + WH2_OFF + ((t + 512) << 4));
  }
  STAGE(0);
  STAGE(1);
  STAGE(2);
  STAGE(3);

  // ---- main loop: 64 K-steps, ring of 5, 1 barrier/step, counted vmcnt.
  // At iter s the wait leaves stages s+1..min(s+3,63) in flight:
  // s<=60 -> vmcnt(9) (also drains the 2 wh2 loads at s=0), 61 -> 6, 62 -> 3, 63 -> 0.
  for (int s = 0; s < 64; ++s) {
    if (s < 61)      asm volatile("s_waitcnt vmcnt(9)" ::: "memory");
    else if (s == 61) asm volatile("s_waitcnt vmcnt(6)" ::: "memory");
    else if (s == 62) asm volatile("s_waitcnt vmcnt(3)" ::: "memory");
    else              asm volatile("s_waitcnt vmcnt(0)" ::: "memory");
    __builtin_amdgcn_s_barrier();
    COMPUTE(s);
    if (s < 60) STAGE(s + 4);
  }

  // ---- epilogue: cross-kq combine via LDS overlay on buffers
  __syncthreads();
  float* sacc = (float*)smem;                  // [2][64][68]
  float* ssum = (float*)(smem + 34816);        // [2][64]
  #pragma unroll
  for (int r = 0; r < 4; ++r) {
    int rr = rq * 16 + g * 4 + r;              // C/D: row = 4*(l>>4)+r, col = l&15
    float* dst = sacc + (kq * 64 + rr) * 68;
    dst[ 0 + lr] = a0[r];
    dst[16 + lr] = a1[r];
    dst[32 + lr] = a2[r];
    dst[48 + lr] = a3[r];
    if (lr == 0) ssum[kq * 64 + rr] = as[r];
  }
  __syncthreads();

  const int row = t >> 3;               // 0..63
  const int c0  = (t & 7) << 3;         // 0..56
  const float* p0 = sacc + row * 68;
  const float* p1 = sacc + (64 + row) * 68;
  float d = ssum[row] + ssum[64 + row];
  float inv = 1.0f / d;
  f32x4 o0, o1;
  #pragma unroll
  for (int j = 0; j < 4; ++j) {
    float x = (p0[c0 + j] + p1[c0 + j]) * inv;
    o0[j] = x > 0.f ? x : expm1f(x);
    float y = (p0[c0 + 4 + j] + p1[c0 + 4 + j]) * inv;
    o1[j] = y > 0.f ? y : expm1f(y);
  }
  size_t ob = ((size_t)((b << 12) + r0 + row) << 6) + c0;
  *(f32x4*)(out + ob)     = o0;
  *(f32x4*)(out + ob + 4) = o1;
}

extern "C" void kernel_launch(void* const* d_in, const int* in_sizes, int n_in,
                              void* d_out, int out_size, void* d_ws, size_t ws_size,
                              hipStream_t stream) {
  const float* h    = (const float*)d_in[0];
  const int*   adj  = (const int*)d_in[1];
  const float* W    = (const float*)d_in[2];
  const float* a    = (const float*)d_in[3];
  const float* bias = (const float*)d_in[4];
  float* out = (float*)d_out;

  char* ws = (char*)d_ws;
  ushort* WhT = (ushort*)ws;                                   // 4*64*4096*2 = 2 MB
  float*  Wh1 = (float*)(ws + (size_t)NB * OUT_F * NN * 2);    // 64 KB
  float*  Wh2 = Wh1 + NB * NN;                                 // 64 KB

  (void)hipFuncSetAttribute((const void*)k2_attn,
                            hipFuncAttributeMaxDynamicSharedMemorySize, LDS_TOTAL);

  k1_gemm<<<dim3(NB * NN / 32), 256, 0, stream>>>(h, W, a, bias, WhT, Wh1, Wh2);
  k2_attn<<<dim3(NN / 64, NB), 512, LDS_TOTAL, stream>>>(adj, WhT, Wh1, Wh2, out);
}